// Round 19
// baseline (1506.762 us; speedup 1.0000x reference)
//
#include <hip/hip_runtime.h>
#include <math.h>

#define NNODES 5000
#define NEDGES 80000
#define NB 8
#define NIN 30
#define K0PAD 32
#define NH 4
#define ND 64
#define NHD 256
#define NT 5
#define NOUT 3
#define ROWS (NB * NNODES) // 40000
#define BNEPS 1e-5f
#define KP 40   // LDS k-stride for A tile (shorts)
#define NREP 64 // sums[] replicas
#define BM 32   // gemm M-tile
#define CSTR 264 // epilogue C-stage row stride (shorts)

// bank-conflict-free position for BN partial channel c (XOR swizzle in low 3 bits)
#define BPOS(c) (((c) & ~7) | (((c) & 7) ^ (((c) >> 5) & 7)))

#define GLOBAL_AS __attribute__((address_space(1)))
#define LDS_AS __attribute__((address_space(3)))

typedef short shortx8 __attribute__((ext_vector_type(8)));
typedef _Float16 halfx8 __attribute__((ext_vector_type(8)));
typedef _Float16 halfx4 __attribute__((ext_vector_type(4)));
typedef _Float16 halfx2 __attribute__((ext_vector_type(2)));
typedef float floatx4 __attribute__((ext_vector_type(4)));
typedef int intx4 __attribute__((ext_vector_type(4)));

static __device__ __forceinline__ unsigned short f2h(float f) {
    union { _Float16 h; unsigned short u; } v;
    v.h = (_Float16)f;
    return v.u;
}
static __device__ __forceinline__ float h2f(unsigned short u) {
    union { _Float16 h; unsigned short u; } v;
    v.u = u;
    return (float)v.h;
}
static __device__ __forceinline__ halfx8 splat8(_Float16 x) {
    return (halfx8){x, x, x, x, x, x, x, x};
}

// ---------------- CSR build ----------------

__global__ void count_kernel(const int* __restrict__ dst, int* __restrict__ counts, int n) {
    int e = blockIdx.x * blockDim.x + threadIdx.x;
    if (e < n) atomicAdd(&counts[dst[e]], 1);
}

__global__ __launch_bounds__(1024) void scan_kernel(const int* __restrict__ counts,
                                                    int* __restrict__ offsets, int n) {
    __shared__ int smem[1024];
    const int CH = 5;
    int tid = threadIdx.x;
    int base = tid * CH;
    int loc[CH];
    int s = 0;
    for (int j = 0; j < CH; ++j) {
        int i = base + j;
        int v = (i < n) ? counts[i] : 0;
        loc[j] = s;
        s += v;
    }
    smem[tid] = s;
    __syncthreads();
    for (int off = 1; off < 1024; off <<= 1) {
        int v = (tid >= off) ? smem[tid - off] : 0;
        __syncthreads();
        smem[tid] += v;
        __syncthreads();
    }
    int excl = smem[tid] - s;
    for (int j = 0; j < CH; ++j) {
        int i = base + j;
        if (i < n) offsets[i] = excl + loc[j];
    }
    if (tid == 1023) offsets[n] = smem[1023];
}

__global__ void fill_kernel(const int* __restrict__ src, const int* __restrict__ dst,
                            const int* __restrict__ offsets, int* __restrict__ cursor,
                            int* __restrict__ csr_src, int n) {
    int e = blockIdx.x * blockDim.x + threadIdx.x;
    if (e >= n) return;
    int d = dst[e];
    int pos = offsets[d] + atomicAdd(&cursor[d], 1);
    csr_src[pos] = src[e];
}

// ---------------- packing + workspace zeroing (one dispatch) ----------------

__global__ void pack_all_kernel(const float* __restrict__ xx,
                                const float* __restrict__ W0, const float* __restrict__ W1,
                                const float* __restrict__ W2, const float* __restrict__ W3,
                                unsigned short* __restrict__ xx16,
                                unsigned short* __restrict__ P0, unsigned short* __restrict__ P1,
                                unsigned short* __restrict__ P2, unsigned short* __restrict__ P3,
                                int* __restrict__ counts, int* __restrict__ cursor,
                                float* __restrict__ sums) {
    int l = blockIdx.y;
    if (l == 4) {
        for (int idx = blockIdx.x * 256 + threadIdx.x; idx < ROWS * K0PAD; idx += 256 * 256) {
            int g = idx >> 5;
            int k = idx & 31;
            float v = (k < NIN) ? xx[(size_t)g * NIN + k] : 0.0f;
            xx16[idx] = f2h(v);
        }
        return;
    }
    if (l == 5) {
        int ti = blockIdx.x * 256 + threadIdx.x;
        for (int i = ti; i < 2 * NNODES; i += 256 * 256) {
            if (i < NNODES) counts[i] = 0;
            else cursor[i - NNODES] = 0;
        }
        for (int i = ti; i < NREP * 2 * NHD; i += 256 * 256) sums[i] = 0.0f;
        return;
    }
    const float* W = (l == 0) ? W0 : (l == 1) ? W1 : (l == 2) ? W2 : W3;
    unsigned short* WtP = (l == 0) ? P0 : (l == 1) ? P1 : (l == 2) ? P2 : P3;
    int Kin = (l == 0) ? NIN : NHD;
    int Kpad = (l == 0) ? K0PAD : NHD;
    int n = blockIdx.x;
    int k = threadIdx.x;
    if (k < Kpad) {
        float v = (k < Kin) ? W[(size_t)k * NHD + n] : 0.0f;
        int t = k >> 5;
        int quad = (k >> 3) & 3;
        int j = k & 7;
        int p = n * 4 + (quad ^ ((n >> 1) & 3));
        WtP[(size_t)t * (NHD * 32) + p * 8 + j] = f2h(v);
    }
}

// ---------------- BN finalize: 64 replicas -> scale/shift table ----------------

__global__ __launch_bounds__(128) void bnfinal_kernel(float* __restrict__ sums,
                                                      const float* __restrict__ gamma,
                                                      const float* __restrict__ beta,
                                                      float* __restrict__ bnss) {
    int c = blockIdx.x * 128 + threadIdx.x;
    float s = 0.0f, s2 = 0.0f;
#pragma unroll 8
    for (int r = 0; r < NREP; ++r) {
        s += sums[r * 2 * NHD + c];
        s2 += sums[r * 2 * NHD + NHD + c];
        sums[r * 2 * NHD + c] = 0.0f;
        sums[r * 2 * NHD + NHD + c] = 0.0f;
    }
    const float invn = 1.0f / (float)ROWS;
    float mu = s * invn;
    float var = s2 * invn - mu * mu;
    float sc = rsqrtf(var + BNEPS) * gamma[c];
    bnss[c] = sc;
    bnss[NHD + c] = beta[c] - mu * sc;
}

// ---------------- MFMA GEMM + fused BN-on-A + fused el/er + OPTIONAL fused headout ----------------
// do_head (layer-0 of steps 1..4): prologue computes previous step's head output
// for this block's OWN 32 rows (block-local: out = Wout . BN(act16[row])), writes
// out[t-1], builds the shifted f16 window straight into the LDS A-tile and
// writes it through to the ping-pong window buffer (race-free: old/new separate).

__global__ __launch_bounds__(256) void gemm_mfma_kernel(
    const unsigned short* __restrict__ A, const unsigned short* __restrict__ Wt,
    const float* __restrict__ alw, const float* __restrict__ arw,
    const float* __restrict__ bnss, int apply_bn,
    unsigned short* __restrict__ C16, float* __restrict__ el, float* __restrict__ er,
    int K, int do_head,
    const unsigned short* __restrict__ act16_in, const float* __restrict__ Wout,
    const float* __restrict__ bout, float* __restrict__ outbuf,
    const unsigned short* __restrict__ xxold, unsigned short* __restrict__ xxnew,
    int tprev) {
    __shared__ __align__(16) short smem_s[BM * KP + NHD * 32]; // As | Bs, reused as Cs
    __shared__ __align__(16) unsigned short bnsc16[NHD];
    __shared__ __align__(16) unsigned short bnsh16[NHD];
    short* As = smem_s;
    short* Bs = smem_s + BM * KP;
    int tid = threadIdx.x;
    int row0 = blockIdx.x * BM;
    if (apply_bn) {
        bnsc16[tid] = f2h(bnss[tid]);
        bnsh16[tid] = f2h(bnss[NHD + tid]);
    }
    if (do_head) {
        // ---- fused headout for rows [row0, row0+32): 8 lanes per row ----
        int rr = tid >> 3;
        int sub = tid & 7;
        int g = row0 + rr;
        int c0 = sub * 32;
        float r0 = 0.f, r1 = 0.f, r2 = 0.f;
#pragma unroll
        for (int j = 0; j < 32; j += 8) {
            halfx8 hv = *(const halfx8*)(act16_in + (size_t)g * NHD + c0 + j);
#pragma unroll
            for (int q = 0; q < 8; ++q) {
                int c = c0 + j + q;
                float x = fmaf((float)hv[q], bnss[c], bnss[NHD + c]);
                x = (x > 0.0f) ? x : 0.01f * x;
                r0 += x * Wout[c * NOUT + 0];
                r1 += x * Wout[c * NOUT + 1];
                r2 += x * Wout[c * NOUT + 2];
            }
        }
#pragma unroll
        for (int o = 1; o < 8; o <<= 1) {
            r0 += __shfl_xor(r0, o);
            r1 += __shfl_xor(r1, o);
            r2 += __shfl_xor(r2, o);
        }
        float o0 = r0 + bout[0], o1 = r1 + bout[1], o2 = r2 + bout[2];
        if (sub == 0) {
            float* op = outbuf + ((size_t)g * NT + tprev) * NOUT;
            op[0] = o0;
            op[1] = o1;
            op[2] = o2;
        }
        // window shift from OLD buffer (ping-pong -> no read/write race)
        unsigned short hw4[4];
#pragma unroll
        for (int j = 0; j < 4; ++j) {
            int k = sub * 4 + j;
            float nv;
            if (k < 27) nv = h2f(xxold[(size_t)g * K0PAD + k + 3]);
            else if (k == 27) nv = o0;
            else if (k == 28) nv = o1;
            else if (k == 29) nv = o2;
            else nv = 0.0f;
            hw4[j] = f2h(nv);
            As[rr * KP + k] = (short)hw4[j];
        }
        *(unsigned long long*)(xxnew + (size_t)g * K0PAD + sub * 4) =
            *(const unsigned long long*)hw4;
    }
    __syncthreads();

    int wave = tid >> 6; // head
    int lane = tid & 63;
    int c = lane & 15;
    int quad = lane >> 4;
    int xorv = (c >> 1) & 3;

    floatx4 acc[2][4];
#pragma unroll
    for (int mt = 0; mt < 2; ++mt)
#pragma unroll
        for (int nt = 0; nt < 4; ++nt) acc[mt][nt] = (floatx4){0.f, 0.f, 0.f, 0.f};

    int r = tid >> 2;   // 0..63 (only <BM used)
    int seg = tid & 3;
    const halfx8 p01 = splat8((_Float16)0.01f);
    for (int k0 = 0; k0 < K; k0 += 32) {
        const unsigned short* gB = Wt + (size_t)(k0 >> 5) * (NHD * 32);
#pragma unroll
        for (int i = 0; i < 4; ++i) {
            int ci = i * 256 + tid;
            __builtin_amdgcn_global_load_lds(
                (const GLOBAL_AS unsigned int*)(gB + ci * 8),
                (LDS_AS unsigned int*)(&Bs[ci * 8]), 16, 0, 0);
        }
        if (r < BM && !do_head) {
            shortx8 v = *(const shortx8*)(A + (size_t)(row0 + r) * K + k0 + seg * 8);
            if (apply_bn) {
                halfx8 hv = *(halfx8*)&v;
                int kg = k0 + seg * 8;
                halfx8 sc = *(const halfx8*)(&bnsc16[kg]);
                halfx8 sh = *(const halfx8*)(&bnsh16[kg]);
                halfx8 x = hv * sc + sh;                    // v_pk_fma_f16
                hv = __builtin_elementwise_max(x, x * p01); // leaky relu, packed
                v = *(shortx8*)&hv;
            }
            *(shortx8*)(&As[r * KP + seg * 8]) = v;
        }
        __syncthreads();
        halfx8 a[2], b[4];
#pragma unroll
        for (int mt = 0; mt < 2; ++mt)
            a[mt] = *(const halfx8*)(&As[(mt * 16 + c) * KP + quad * 8]);
#pragma unroll
        for (int nt = 0; nt < 4; ++nt) {
            int pq = (wave * 64 + nt * 16 + c) * 4 + (quad ^ xorv);
            b[nt] = *(const halfx8*)(&Bs[pq * 8]);
        }
#pragma unroll
        for (int mt = 0; mt < 2; ++mt)
#pragma unroll
            for (int nt = 0; nt < 4; ++nt)
                acc[mt][nt] = __builtin_amdgcn_mfma_f32_16x16x32_f16(a[mt], b[nt],
                                                                     acc[mt][nt], 0, 0, 0);
        __syncthreads();
    }

    // epilogue: stage f16 C in LDS (reuse smem), fused el/er from fp32 acc
    short* Cs = smem_s;
    float alv[4], arv[4];
#pragma unroll
    for (int nt = 0; nt < 4; ++nt) {
        alv[nt] = alw[wave * 64 + nt * 16 + c];
        arv[nt] = arw[wave * 64 + nt * 16 + c];
    }
#pragma unroll
    for (int mt = 0; mt < 2; ++mt) {
#pragma unroll
        for (int rr = 0; rr < 4; ++rr) {
            int rl = mt * 16 + quad * 4 + rr;
            int row = row0 + rl;
            float pl = 0.0f, pr = 0.0f;
#pragma unroll
            for (int nt = 0; nt < 4; ++nt) {
                float v = acc[mt][nt][rr];
                Cs[rl * CSTR + wave * 64 + nt * 16 + c] = (short)f2h(v);
                pl += v * alv[nt];
                pr += v * arv[nt];
            }
#pragma unroll
            for (int o = 1; o < 16; o <<= 1) {
                pl += __shfl_xor(pl, o);
                pr += __shfl_xor(pr, o);
            }
            if (c == mt * 4 + rr) {
                el[(size_t)row * NH + wave] = pl;
                er[(size_t)row * NH + wave] = pr;
            }
        }
    }
    __syncthreads();
#pragma unroll
    for (int i = 0; i < 4; ++i) {
        int rl = i * 8 + (tid >> 5);
        int col = (tid & 31) * 8;
        shortx8 vv = *(const shortx8*)(&Cs[rl * CSTR + col]);
        *(shortx8*)(&C16[(size_t)(row0 + rl) * NHD + col]) = vv;
    }
}

// ---------------- edge softmax + aggregate + BN partials ----------------
// 512 thr = 8 waves = 8 nodes/block. BPOS XOR swizzle on BN partials.

__global__ __launch_bounds__(512) void attn_kernel(const unsigned short* __restrict__ h16,
                                                   const float* __restrict__ el,
                                                   const float* __restrict__ er,
                                                   const int* __restrict__ offsets,
                                                   const int* __restrict__ csr_src,
                                                   unsigned short* __restrict__ out16,
                                                   float* __restrict__ sums_cur) {
    __shared__ float bnpart[8][2][NHD]; // 16 KB
    int p = blockIdx.x;              // 0..4999
    int tid = threadIdx.x;
    int b = p & 7;
    int wave = tid >> 6;             // 0..7 = node within block
    int lane = tid & 63;
    int head = lane >> 4;
    int li = lane & 15;
    int n = ((p >> 3) << 3) + wave;  // 625*8 = 5000 nodes
    int g = b * NNODES + n;
    int start = offsets[n];
    int deg = offsets[n + 1] - start;
    const float* elb = el + (size_t)b * NNODES * NH;
    float er_nh = er[(size_t)g * NH + head];
    float* bw = &bnpart[wave][0][0];

    if (deg == 0) {
        *(unsigned long long*)(out16 + (size_t)g * NHD + lane * 4) = 0ULL;
        int c4 = lane * 4;
#pragma unroll
        for (int j = 0; j < 4; ++j) {
            bw[BPOS(c4 + j)] = 0.0f;
            bw[NHD + BPOS(c4 + j)] = 0.0f;
        }
    } else if (deg <= 64) {
        float e[4], w[4];
        int s[4];
#pragma unroll
        for (int k = 0; k < 4; ++k) {
            int idx = k * 16 + li;
            if (idx < deg) {
                s[k] = csr_src[start + idx];
                float t = elb[s[k] * NH + head] + er_nh;
                e[k] = (t > 0.0f) ? t : 0.2f * t;
            } else {
                s[k] = 0;
                e[k] = -INFINITY;
            }
        }
        float mx = fmaxf(fmaxf(e[0], e[1]), fmaxf(e[2], e[3]));
#pragma unroll
        for (int o = 8; o; o >>= 1) mx = fmaxf(mx, __shfl_xor(mx, o));
        float sm = 0.0f;
#pragma unroll
        for (int k = 0; k < 4; ++k) {
            w[k] = __expf(e[k] - mx);
            sm += w[k];
        }
#pragma unroll
        for (int o = 8; o; o >>= 1) sm += __shfl_xor(sm, o);
        float invsm = 1.0f / sm;
#pragma unroll
        for (int k = 0; k < 4; ++k) w[k] *= invsm;

        int sub = lane >> 5;
        int i32 = lane & 31;
        int hsel = (lane & 24) << 1;
        const unsigned short* hrow = h16 + (size_t)b * NNODES * NHD + i32 * 8;
        halfx8 acc = splat8((_Float16)0.0f);
#define GATHER_CHUNK(K)                                                          \
        if (deg > (K) * 16) {                                                    \
            int cnt = deg - (K) * 16;                                            \
            cnt = (cnt > 16) ? 16 : cnt;                                         \
            int j = 0;                                                           \
            for (; j + 4 <= cnt; j += 4) {                                       \
                int sa = __shfl(s[K], j + sub, 64);                              \
                float wa = __shfl(w[K], hsel + j + sub, 64);                     \
                int sb = __shfl(s[K], j + 2 + sub, 64);                          \
                float wb = __shfl(w[K], hsel + j + 2 + sub, 64);                 \
                halfx8 ha = *(const halfx8*)(hrow + (size_t)sa * NHD);           \
                halfx8 hb = *(const halfx8*)(hrow + (size_t)sb * NHD);           \
                acc += ha * splat8((_Float16)wa);                                \
                acc += hb * splat8((_Float16)wb);                                \
            }                                                                    \
            for (; j < cnt; j += 2) {                                            \
                int e2 = j + sub;                                                \
                bool valid = (e2 < cnt);                                         \
                int ec = valid ? e2 : (cnt - 1);                                 \
                int sa = __shfl(s[K], ec, 64);                                   \
                float wa0 = __shfl(w[K], hsel + ec, 64);                         \
                float wa = valid ? wa0 : 0.0f;                                   \
                halfx8 ha = *(const halfx8*)(hrow + (size_t)sa * NHD);           \
                acc += ha * splat8((_Float16)wa);                                \
            }                                                                    \
        }
        GATHER_CHUNK(0)
        GATHER_CHUNK(1)
        GATHER_CHUNK(2)
        GATHER_CHUNK(3)
#undef GATHER_CHUNK
        intx4 ai = *(intx4*)&acc;
        intx4 bi;
        bi[0] = __shfl_xor(ai[0], 32, 64);
        bi[1] = __shfl_xor(ai[1], 32, 64);
        bi[2] = __shfl_xor(ai[2], 32, 64);
        bi[3] = __shfl_xor(ai[3], 32, 64);
        acc += *(halfx8*)&bi;
        if (sub == 0) {
            *(halfx8*)(out16 + (size_t)g * NHD + i32 * 8) = acc;
            int c8 = i32 * 8;
            int xj = (i32 >> 2) & 7; // store channel c8+j at BPOS(c8+j)
#pragma unroll
            for (int j = 0; j < 8; ++j) {
                float v = (float)acc[j];
                bw[c8 + (j ^ xj)] = v;
                bw[NHD + c8 + (j ^ xj)] = v * v;
            }
        }
    } else {
        const unsigned short* hbase = h16 + (size_t)b * NNODES * NHD + lane * 4;
        float mx = -INFINITY;
        for (int i = li; i < deg; i += 16) {
            int s2 = csr_src[start + i];
            float t = elb[s2 * NH + head] + er_nh;
            t = (t > 0.0f) ? t : 0.2f * t;
            mx = fmaxf(mx, t);
        }
#pragma unroll
        for (int o = 8; o; o >>= 1) mx = fmaxf(mx, __shfl_xor(mx, o));
        float sm = 0.0f;
        for (int i = li; i < deg; i += 16) {
            int s2 = csr_src[start + i];
            float t = elb[s2 * NH + head] + er_nh;
            t = (t > 0.0f) ? t : 0.2f * t;
            sm += __expf(t - mx);
        }
#pragma unroll
        for (int o = 8; o; o >>= 1) sm += __shfl_xor(sm, o);
        float a0 = 0.f, a1 = 0.f, a2 = 0.f, a3 = 0.f;
        for (int j = 0; j < deg; ++j) {
            int s2 = csr_src[start + j];
            float t = elb[s2 * NH + head] + er_nh;
            t = (t > 0.0f) ? t : 0.2f * t;
            float wj = __expf(t - mx);
            halfx4 hv = *(const halfx4*)(hbase + (size_t)s2 * NHD);
            a0 += wj * (float)hv[0];
            a1 += wj * (float)hv[1];
            a2 += wj * (float)hv[2];
            a3 += wj * (float)hv[3];
        }
        float inv = 1.0f / sm;
        halfx4 o4;
        o4[0] = (_Float16)(a0 * inv);
        o4[1] = (_Float16)(a1 * inv);
        o4[2] = (_Float16)(a2 * inv);
        o4[3] = (_Float16)(a3 * inv);
        *(halfx4*)(out16 + (size_t)g * NHD + lane * 4) = o4;
        int c4 = lane * 4;
#pragma unroll
        for (int j = 0; j < 4; ++j) {
            float v = (float)o4[j];
            bw[BPOS(c4 + j)] = v;
            bw[NHD + BPOS(c4 + j)] = v * v;
        }
    }
    __syncthreads();
    {
        int c = tid & 255;
        int half = tid >> 8;
        int pc = BPOS(c);
        float s = 0.0f;
#pragma unroll
        for (int w2 = 0; w2 < 8; ++w2) s += bnpart[w2][half][pc];
        float* sr = sums_cur + (p & (NREP - 1)) * 2 * NHD;
        atomicAdd(&sr[half * NHD + c], s);
    }
}

// ---------------- final output head (t=4 only; no window shift needed) ----------------

__global__ __launch_bounds__(256) void headout_kernel(const unsigned short* __restrict__ x16,
                                                      const float* __restrict__ bnss,
                                                      const float* __restrict__ Wout,
                                                      const float* __restrict__ bout,
                                                      float* __restrict__ out, int t) {
    __shared__ float bsc[NHD];
    __shared__ float bsh[NHD];
    {
        int c = threadIdx.x;
        bsc[c] = bnss[c];
        bsh[c] = bnss[NHD + c];
    }
    __syncthreads();

    int wave = threadIdx.x >> 6;
    int lane = threadIdx.x & 63;
    int g = blockIdx.x * 4 + wave;
    int c0 = lane * 4;
    halfx4 hv = *(const halfx4*)(x16 + (size_t)g * NHD + c0);
    float vv[4];
#pragma unroll
    for (int j = 0; j < 4; ++j) {
        float x = fmaf((float)hv[j], bsc[c0 + j], bsh[c0 + j]);
        vv[j] = (x > 0.0f) ? x : 0.01f * x;
    }
    float r0 = vv[0] * Wout[(c0 + 0) * NOUT + 0] + vv[1] * Wout[(c0 + 1) * NOUT + 0] +
               vv[2] * Wout[(c0 + 2) * NOUT + 0] + vv[3] * Wout[(c0 + 3) * NOUT + 0];
    float r1 = vv[0] * Wout[(c0 + 0) * NOUT + 1] + vv[1] * Wout[(c0 + 1) * NOUT + 1] +
               vv[2] * Wout[(c0 + 2) * NOUT + 1] + vv[3] * Wout[(c0 + 3) * NOUT + 1];
    float r2 = vv[0] * Wout[(c0 + 0) * NOUT + 2] + vv[1] * Wout[(c0 + 1) * NOUT + 2] +
               vv[2] * Wout[(c0 + 2) * NOUT + 2] + vv[3] * Wout[(c0 + 3) * NOUT + 2];
#pragma unroll
    for (int o = 32; o; o >>= 1) {
        r0 += __shfl_xor(r0, o);
        r1 += __shfl_xor(r1, o);
        r2 += __shfl_xor(r2, o);
    }
    if (lane == 0) {
        float* op = out + ((size_t)g * NT + t) * NOUT;
        op[0] = r0 + bout[0];
        op[1] = r1 + bout[1];
        op[2] = r2 + bout[2];
    }
}

// ---------------- launch ----------------

extern "C" void kernel_launch(void* const* d_in, const int* in_sizes, int n_in,
                              void* d_out, int out_size, void* d_ws, size_t ws_size,
                              hipStream_t stream) {
    const float* xx = (const float*)d_in[0];
    const int* src = (const int*)d_in[1];
    const int* dst = (const int*)d_in[2];
    const float* W[4] = {(const float*)d_in[3], (const float*)d_in[8],
                         (const float*)d_in[13], (const float*)d_in[18]};
    const float* al[4] = {(const float*)d_in[4], (const float*)d_in[9],
                          (const float*)d_in[14], (const float*)d_in[19]};
    const float* ar[4] = {(const float*)d_in[5], (const float*)d_in[10],
                          (const float*)d_in[15], (const float*)d_in[20]};
    const float* gamma[4] = {(const float*)d_in[6], (const float*)d_in[11],
                             (const float*)d_in[16], (const float*)d_in[21]};
    const float* beta[4] = {(const float*)d_in[7], (const float*)d_in[12],
                            (const float*)d_in[17], (const float*)d_in[22]};
    const float* W_out = (const float*)d_in[23];
    const float* b_out = (const float*)d_in[24];
    float* out = (float*)d_out;

    // workspace carve
    float* wsf = (float*)d_ws;
    float* el = wsf;                                        // ROWS*NH
    float* er = el + (size_t)ROWS * NH;                     // ROWS*NH
    float* sums = er + (size_t)ROWS * NH;                   // NREP*2*NHD
    float* bnss = sums + NREP * 2 * NHD;                    // 2*NHD (scale|shift)
    unsigned short* h16 = (unsigned short*)(bnss + 2 * NHD); // ROWS*NHD
    unsigned short* act16 = h16 + (size_t)ROWS * NHD;       // ROWS*NHD (attn out)
    unsigned short* xx16a = act16 + (size_t)ROWS * NHD;     // ROWS*K0PAD (window ping)
    unsigned short* xx16b = xx16a + (size_t)ROWS * K0PAD;   // ROWS*K0PAD (window pong)
    unsigned short* Wt0 = xx16b + (size_t)ROWS * K0PAD;     // 256*K0PAD
    unsigned short* Wt1 = Wt0 + 256 * K0PAD;                // 256*256
    unsigned short* Wt2 = Wt1 + 256 * NHD;
    unsigned short* Wt3 = Wt2 + 256 * NHD;
    int* counts = (int*)(Wt3 + 256 * NHD);                  // NNODES
    int* offsets = counts + NNODES;                         // NNODES+1 (+pad)
    int* cursor = offsets + NNODES + 8;                     // NNODES
    int* csr_src = cursor + NNODES;                         // NEDGES
    const unsigned short* Wt[4] = {Wt0, Wt1, Wt2, Wt3};

    // ---- pack + zero (first), then CSR build ----
    pack_all_kernel<<<dim3(256, 6), 256, 0, stream>>>(xx, W[0], W[1], W[2], W[3],
                                                      xx16a,
                                                      (unsigned short*)Wt0,
                                                      (unsigned short*)Wt1,
                                                      (unsigned short*)Wt2,
                                                      (unsigned short*)Wt3,
                                                      counts, cursor, sums);
    count_kernel<<<(NEDGES + 255) / 256, 256, 0, stream>>>(dst, counts, NEDGES);
    scan_kernel<<<1, 1024, 0, stream>>>(counts, offsets, NNODES);
    fill_kernel<<<(NEDGES + 255) / 256, 256, 0, stream>>>(src, dst, offsets, cursor,
                                                          csr_src, NEDGES);

    for (int t = 0; t < NT; ++t) {
        for (int l = 0; l < 4; ++l) {
            int K = (l == 0) ? K0PAD : NHD;
            int apply_bn = (l > 0) ? 1 : 0;
            if (l == 0 && t > 0) {
                // merged: headout(t-1) + layer-0 GEMM (window built in-block)
                const unsigned short* xxold = (t & 1) ? xx16a : xx16b;
                unsigned short* xxnew = (t & 1) ? xx16b : xx16a;
                gemm_mfma_kernel<<<ROWS / BM, 256, 0, stream>>>(
                    xxold, Wt[0], al[0], ar[0], bnss, 0, h16, el, er, K,
                    1, act16, W_out, b_out, out, xxold, xxnew, t - 1);
            } else {
                const unsigned short* A16 = (l == 0) ? xx16a : act16;
                gemm_mfma_kernel<<<ROWS / BM, 256, 0, stream>>>(
                    A16, Wt[l], al[l], ar[l], bnss, apply_bn, h16, el, er, K,
                    0, nullptr, nullptr, nullptr, nullptr, nullptr, nullptr, 0);
            }
            attn_kernel<<<ROWS / 8, 512, 0, stream>>>(h16, el, er, offsets, csr_src,
                                                      act16, sums);
            bnfinal_kernel<<<2, 128, 0, stream>>>(sums, gamma[l], beta[l], bnss);
        }
    }
    headout_kernel<<<ROWS / 4, 256, 0, stream>>>(act16, bnss, W_out, b_out, out, NT - 1);
}

// Round 20
// 1276.853 us; speedup vs baseline: 1.1801x; 1.1801x over previous
//
#include <hip/hip_runtime.h>
#include <math.h>

#define NNODES 5000
#define NEDGES 80000
#define NB 8
#define NIN 30
#define K0PAD 32
#define NH 4
#define ND 64
#define NHD 256
#define NT 5
#define NOUT 3
#define ROWS (NB * NNODES) // 40000
#define BNEPS 1e-5f
#define KP 40   // LDS k-stride for A tile (shorts)
#define NREP 64 // sums[] replicas
#define BM 32   // gemm M-tile
#define CSTR 264 // epilogue C-stage row stride (shorts)

// bank-conflict-free position for BN partial channel c (XOR swizzle in low 3 bits)
#define BPOS(c) (((c) & ~7) | (((c) & 7) ^ (((c) >> 5) & 7)))

#define GLOBAL_AS __attribute__((address_space(1)))
#define LDS_AS __attribute__((address_space(3)))

typedef short shortx8 __attribute__((ext_vector_type(8)));
typedef _Float16 halfx8 __attribute__((ext_vector_type(8)));
typedef _Float16 halfx4 __attribute__((ext_vector_type(4)));
typedef _Float16 halfx2 __attribute__((ext_vector_type(2)));
typedef float floatx4 __attribute__((ext_vector_type(4)));
typedef int intx4 __attribute__((ext_vector_type(4)));

static __device__ __forceinline__ unsigned short f2h(float f) {
    union { _Float16 h; unsigned short u; } v;
    v.h = (_Float16)f;
    return v.u;
}
static __device__ __forceinline__ float h2f(unsigned short u) {
    union { _Float16 h; unsigned short u; } v;
    v.u = u;
    return (float)v.h;
}
static __device__ __forceinline__ halfx8 splat8(_Float16 x) {
    return (halfx8){x, x, x, x, x, x, x, x};
}

// ---------------- CSR build ----------------

__global__ void count_kernel(const int* __restrict__ dst, int* __restrict__ counts, int n) {
    int e = blockIdx.x * blockDim.x + threadIdx.x;
    if (e < n) atomicAdd(&counts[dst[e]], 1);
}

__global__ __launch_bounds__(1024) void scan_kernel(const int* __restrict__ counts,
                                                    int* __restrict__ offsets, int n) {
    __shared__ int smem[1024];
    const int CH = 5;
    int tid = threadIdx.x;
    int base = tid * CH;
    int loc[CH];
    int s = 0;
    for (int j = 0; j < CH; ++j) {
        int i = base + j;
        int v = (i < n) ? counts[i] : 0;
        loc[j] = s;
        s += v;
    }
    smem[tid] = s;
    __syncthreads();
    for (int off = 1; off < 1024; off <<= 1) {
        int v = (tid >= off) ? smem[tid - off] : 0;
        __syncthreads();
        smem[tid] += v;
        __syncthreads();
    }
    int excl = smem[tid] - s;
    for (int j = 0; j < CH; ++j) {
        int i = base + j;
        if (i < n) offsets[i] = excl + loc[j];
    }
    if (tid == 1023) offsets[n] = smem[1023];
}

__global__ void fill_kernel(const int* __restrict__ src, const int* __restrict__ dst,
                            const int* __restrict__ offsets, int* __restrict__ cursor,
                            int* __restrict__ csr_src, int n) {
    int e = blockIdx.x * blockDim.x + threadIdx.x;
    if (e >= n) return;
    int d = dst[e];
    int pos = offsets[d] + atomicAdd(&cursor[d], 1);
    csr_src[pos] = src[e];
}

// ---------------- packing + workspace zeroing (one dispatch) ----------------
// y<4: WtP layers (16B chunks, swizzled pos p = n*4 + (quad ^ ((n>>1)&3))).
// y==4: xx -> f16 padded window.  y==5: zero counts/cursor/sums.

__global__ void pack_all_kernel(const float* __restrict__ xx,
                                const float* __restrict__ W0, const float* __restrict__ W1,
                                const float* __restrict__ W2, const float* __restrict__ W3,
                                unsigned short* __restrict__ xx16,
                                unsigned short* __restrict__ P0, unsigned short* __restrict__ P1,
                                unsigned short* __restrict__ P2, unsigned short* __restrict__ P3,
                                int* __restrict__ counts, int* __restrict__ cursor,
                                float* __restrict__ sums) {
    int l = blockIdx.y;
    if (l == 4) {
        for (int idx = blockIdx.x * 256 + threadIdx.x; idx < ROWS * K0PAD; idx += 256 * 256) {
            int g = idx >> 5;
            int k = idx & 31;
            float v = (k < NIN) ? xx[(size_t)g * NIN + k] : 0.0f;
            xx16[idx] = f2h(v);
        }
        return;
    }
    if (l == 5) {
        int ti = blockIdx.x * 256 + threadIdx.x;
        for (int i = ti; i < 2 * NNODES; i += 256 * 256) {
            if (i < NNODES) counts[i] = 0;
            else cursor[i - NNODES] = 0;
        }
        for (int i = ti; i < NREP * 2 * NHD; i += 256 * 256) sums[i] = 0.0f;
        return;
    }
    const float* W = (l == 0) ? W0 : (l == 1) ? W1 : (l == 2) ? W2 : W3;
    unsigned short* WtP = (l == 0) ? P0 : (l == 1) ? P1 : (l == 2) ? P2 : P3;
    int Kin = (l == 0) ? NIN : NHD;
    int Kpad = (l == 0) ? K0PAD : NHD;
    int n = blockIdx.x;
    int k = threadIdx.x;
    if (k < Kpad) {
        float v = (k < Kin) ? W[(size_t)k * NHD + n] : 0.0f;
        int t = k >> 5;
        int quad = (k >> 3) & 3;
        int j = k & 7;
        int p = n * 4 + (quad ^ ((n >> 1) & 3));
        WtP[(size_t)t * (NHD * 32) + p * 8 + j] = f2h(v);
    }
}

// ---------------- BN finalize: 64 replicas -> scale/shift table ----------------
// 2 blocks x 128 thr (parallelism on the 128-load/thread latency chain).

__global__ __launch_bounds__(128) void bnfinal_kernel(float* __restrict__ sums,
                                                      const float* __restrict__ gamma,
                                                      const float* __restrict__ beta,
                                                      float* __restrict__ bnss) {
    int c = blockIdx.x * 128 + threadIdx.x;
    float s = 0.0f, s2 = 0.0f;
#pragma unroll 8
    for (int r = 0; r < NREP; ++r) {
        s += sums[r * 2 * NHD + c];
        s2 += sums[r * 2 * NHD + NHD + c];
        sums[r * 2 * NHD + c] = 0.0f;
        sums[r * 2 * NHD + NHD + c] = 0.0f;
    }
    const float invn = 1.0f / (float)ROWS;
    float mu = s * invn;
    float var = s2 * invn - mu * mu;
    float sc = rsqrtf(var + BNEPS) * gamma[c];
    bnss[c] = sc;
    bnss[NHD + c] = beta[c] - mu * sc;
}

// ---------------- MFMA GEMM + fused BN(prev layer, packed f16) + fused el/er ----------------

__global__ __launch_bounds__(256) void gemm_mfma_kernel(
    const unsigned short* __restrict__ A, const unsigned short* __restrict__ Wt,
    const float* __restrict__ alw, const float* __restrict__ arw,
    const float* __restrict__ bnss, int apply_bn,
    unsigned short* __restrict__ C16, float* __restrict__ el, float* __restrict__ er,
    int K) {
    __shared__ __align__(16) short smem_s[BM * KP + NHD * 32]; // As | Bs, reused as Cs
    __shared__ __align__(16) unsigned short bnsc16[NHD];
    __shared__ __align__(16) unsigned short bnsh16[NHD];
    short* As = smem_s;
    short* Bs = smem_s + BM * KP;
    int tid = threadIdx.x;
    if (apply_bn) {
        bnsc16[tid] = f2h(bnss[tid]);
        bnsh16[tid] = f2h(bnss[NHD + tid]);
    }
    __syncthreads();

    int wave = tid >> 6; // head
    int lane = tid & 63;
    int c = lane & 15;
    int quad = lane >> 4;
    int xorv = (c >> 1) & 3;
    int row0 = blockIdx.x * BM;

    floatx4 acc[2][4];
#pragma unroll
    for (int mt = 0; mt < 2; ++mt)
#pragma unroll
        for (int nt = 0; nt < 4; ++nt) acc[mt][nt] = (floatx4){0.f, 0.f, 0.f, 0.f};

    int r = tid >> 2;   // 0..63 (only <BM used)
    int seg = tid & 3;
    const halfx8 p01 = splat8((_Float16)0.01f);
    for (int k0 = 0; k0 < K; k0 += 32) {
        const unsigned short* gB = Wt + (size_t)(k0 >> 5) * (NHD * 32);
#pragma unroll
        for (int i = 0; i < 4; ++i) {
            int ci = i * 256 + tid;
            __builtin_amdgcn_global_load_lds(
                (const GLOBAL_AS unsigned int*)(gB + ci * 8),
                (LDS_AS unsigned int*)(&Bs[ci * 8]), 16, 0, 0);
        }
        if (r < BM) {
            shortx8 v = *(const shortx8*)(A + (size_t)(row0 + r) * K + k0 + seg * 8);
            if (apply_bn) {
                halfx8 hv = *(halfx8*)&v;
                int kg = k0 + seg * 8;
                halfx8 sc = *(const halfx8*)(&bnsc16[kg]);
                halfx8 sh = *(const halfx8*)(&bnsh16[kg]);
                halfx8 x = hv * sc + sh;                    // v_pk_fma_f16
                hv = __builtin_elementwise_max(x, x * p01); // leaky relu, packed
                v = *(shortx8*)&hv;
            }
            *(shortx8*)(&As[r * KP + seg * 8]) = v;
        }
        __syncthreads();
        halfx8 a[2], b[4];
#pragma unroll
        for (int mt = 0; mt < 2; ++mt)
            a[mt] = *(const halfx8*)(&As[(mt * 16 + c) * KP + quad * 8]);
#pragma unroll
        for (int nt = 0; nt < 4; ++nt) {
            int pq = (wave * 64 + nt * 16 + c) * 4 + (quad ^ xorv);
            b[nt] = *(const halfx8*)(&Bs[pq * 8]);
        }
#pragma unroll
        for (int mt = 0; mt < 2; ++mt)
#pragma unroll
            for (int nt = 0; nt < 4; ++nt)
                acc[mt][nt] = __builtin_amdgcn_mfma_f32_16x16x32_f16(a[mt], b[nt],
                                                                     acc[mt][nt], 0, 0, 0);
        __syncthreads();
    }

    // epilogue: stage f16 C in LDS (reuse smem), fused el/er from fp32 acc
    short* Cs = smem_s;
    float alv[4], arv[4];
#pragma unroll
    for (int nt = 0; nt < 4; ++nt) {
        alv[nt] = alw[wave * 64 + nt * 16 + c];
        arv[nt] = arw[wave * 64 + nt * 16 + c];
    }
#pragma unroll
    for (int mt = 0; mt < 2; ++mt) {
#pragma unroll
        for (int rr = 0; rr < 4; ++rr) {
            int rl = mt * 16 + quad * 4 + rr;
            int row = row0 + rl;
            float pl = 0.0f, pr = 0.0f;
#pragma unroll
            for (int nt = 0; nt < 4; ++nt) {
                float v = acc[mt][nt][rr];
                Cs[rl * CSTR + wave * 64 + nt * 16 + c] = (short)f2h(v);
                pl += v * alv[nt];
                pr += v * arv[nt];
            }
#pragma unroll
            for (int o = 1; o < 16; o <<= 1) {
                pl += __shfl_xor(pl, o);
                pr += __shfl_xor(pr, o);
            }
            if (c == mt * 4 + rr) {
                el[(size_t)row * NH + wave] = pl;
                er[(size_t)row * NH + wave] = pr;
            }
        }
    }
    __syncthreads();
#pragma unroll
    for (int i = 0; i < 4; ++i) {
        int rl = i * 8 + (tid >> 5);
        int col = (tid & 31) * 8;
        shortx8 vv = *(const shortx8*)(&Cs[rl * CSTR + col]);
        *(shortx8*)(&C16[(size_t)(row0 + rl) * NHD + col]) = vv;
    }
}

// ---------------- edge softmax + aggregate + BN partials ----------------
// 512 thr = 8 waves = 8 nodes/block. Wave per node; phase 1 fp32 logits
// (weights pre-normalized); phase 2 packed-f16 coalesced gather.
// BN partials in LDS with BPOS XOR swizzle (kills the stride-8 8-way conflict).

__global__ __launch_bounds__(512) void attn_kernel(const unsigned short* __restrict__ h16,
                                                   const float* __restrict__ el,
                                                   const float* __restrict__ er,
                                                   const int* __restrict__ offsets,
                                                   const int* __restrict__ csr_src,
                                                   unsigned short* __restrict__ out16,
                                                   float* __restrict__ sums_cur) {
    __shared__ float bnpart[8][2][NHD]; // 16 KB
    int p = blockIdx.x;              // 0..4999
    int tid = threadIdx.x;
    int b = p & 7;
    int wave = tid >> 6;             // 0..7 = node within block
    int lane = tid & 63;
    int head = lane >> 4;
    int li = lane & 15;
    int n = ((p >> 3) << 3) + wave;  // 625*8 = 5000 nodes
    int g = b * NNODES + n;
    int start = offsets[n];
    int deg = offsets[n + 1] - start;
    const float* elb = el + (size_t)b * NNODES * NH;
    float er_nh = er[(size_t)g * NH + head];
    float* bw = &bnpart[wave][0][0];

    if (deg == 0) {
        *(unsigned long long*)(out16 + (size_t)g * NHD + lane * 4) = 0ULL;
        int c4 = lane * 4;
#pragma unroll
        for (int j = 0; j < 4; ++j) {
            bw[BPOS(c4 + j)] = 0.0f;
            bw[NHD + BPOS(c4 + j)] = 0.0f;
        }
    } else if (deg <= 64) {
        // phase 1 (fp32): lane li of each head-group owns edges li+16k
        float e[4], w[4];
        int s[4];
#pragma unroll
        for (int k = 0; k < 4; ++k) {
            int idx = k * 16 + li;
            if (idx < deg) {
                s[k] = csr_src[start + idx];
                float t = elb[s[k] * NH + head] + er_nh;
                e[k] = (t > 0.0f) ? t : 0.2f * t;
            } else {
                s[k] = 0;
                e[k] = -INFINITY;
            }
        }
        float mx = fmaxf(fmaxf(e[0], e[1]), fmaxf(e[2], e[3]));
#pragma unroll
        for (int o = 8; o; o >>= 1) mx = fmaxf(mx, __shfl_xor(mx, o));
        float sm = 0.0f;
#pragma unroll
        for (int k = 0; k < 4; ++k) {
            w[k] = __expf(e[k] - mx); // exp(-inf)=0 pads invalid slots
            sm += w[k];
        }
#pragma unroll
        for (int o = 8; o; o >>= 1) sm += __shfl_xor(sm, o);
        // pre-normalize: own head's denominator == channel head's for broadcast readers
        float invsm = 1.0f / sm;
#pragma unroll
        for (int k = 0; k < 4; ++k) w[k] *= invsm;

        // phase 2: sub = (lane>>5) serves edges j+sub; i32 = lane&31 -> 8 channels
        int sub = lane >> 5;
        int i32 = lane & 31;
        int hsel = (lane & 24) << 1; // channel head (i32>>3) * 16
        const unsigned short* hrow = h16 + (size_t)b * NNODES * NHD + i32 * 8;
        halfx8 acc = splat8((_Float16)0.0f);
#define GATHER_CHUNK(K)                                                          \
        if (deg > (K) * 16) {                                                    \
            int cnt = deg - (K) * 16;                                            \
            cnt = (cnt > 16) ? 16 : cnt;                                         \
            int j = 0;                                                           \
            for (; j + 4 <= cnt; j += 4) {                                       \
                int sa = __shfl(s[K], j + sub, 64);                              \
                float wa = __shfl(w[K], hsel + j + sub, 64);                     \
                int sb = __shfl(s[K], j + 2 + sub, 64);                          \
                float wb = __shfl(w[K], hsel + j + 2 + sub, 64);                 \
                halfx8 ha = *(const halfx8*)(hrow + (size_t)sa * NHD);           \
                halfx8 hb = *(const halfx8*)(hrow + (size_t)sb * NHD);           \
                acc += ha * splat8((_Float16)wa);                                \
                acc += hb * splat8((_Float16)wb);                                \
            }                                                                    \
            for (; j < cnt; j += 2) {                                            \
                int e2 = j + sub;                                                \
                bool valid = (e2 < cnt);                                         \
                int ec = valid ? e2 : (cnt - 1);                                 \
                int sa = __shfl(s[K], ec, 64);                                   \
                float wa0 = __shfl(w[K], hsel + ec, 64);                         \
                float wa = valid ? wa0 : 0.0f;                                   \
                halfx8 ha = *(const halfx8*)(hrow + (size_t)sa * NHD);           \
                acc += ha * splat8((_Float16)wa);                                \
            }                                                                    \
        }
        GATHER_CHUNK(0)
        GATHER_CHUNK(1)
        GATHER_CHUNK(2)
        GATHER_CHUNK(3)
#undef GATHER_CHUNK
        intx4 ai = *(intx4*)&acc;
        intx4 bi;
        bi[0] = __shfl_xor(ai[0], 32, 64);
        bi[1] = __shfl_xor(ai[1], 32, 64);
        bi[2] = __shfl_xor(ai[2], 32, 64);
        bi[3] = __shfl_xor(ai[3], 32, 64);
        acc += *(halfx8*)&bi;
        if (sub == 0) {
            *(halfx8*)(out16 + (size_t)g * NHD + i32 * 8) = acc;
            int c8 = i32 * 8;
            int xj = (i32 >> 2) & 7; // store channel c8+j at BPOS(c8+j)
#pragma unroll
            for (int j = 0; j < 8; ++j) {
                float v = (float)acc[j];
                bw[c8 + (j ^ xj)] = v;
                bw[NHD + c8 + (j ^ xj)] = v * v;
            }
        }
    } else {
        // generic fallback (deg > 64, rare) — fp32 path
        const unsigned short* hbase = h16 + (size_t)b * NNODES * NHD + lane * 4;
        float mx = -INFINITY;
        for (int i = li; i < deg; i += 16) {
            int s2 = csr_src[start + i];
            float t = elb[s2 * NH + head] + er_nh;
            t = (t > 0.0f) ? t : 0.2f * t;
            mx = fmaxf(mx, t);
        }
#pragma unroll
        for (int o = 8; o; o >>= 1) mx = fmaxf(mx, __shfl_xor(mx, o));
        float sm = 0.0f;
        for (int i = li; i < deg; i += 16) {
            int s2 = csr_src[start + i];
            float t = elb[s2 * NH + head] + er_nh;
            t = (t > 0.0f) ? t : 0.2f * t;
            sm += __expf(t - mx);
        }
#pragma unroll
        for (int o = 8; o; o >>= 1) sm += __shfl_xor(sm, o);
        float a0 = 0.f, a1 = 0.f, a2 = 0.f, a3 = 0.f;
        for (int j = 0; j < deg; ++j) {
            int s2 = csr_src[start + j];
            float t = elb[s2 * NH + head] + er_nh;
            t = (t > 0.0f) ? t : 0.2f * t;
            float wj = __expf(t - mx);
            halfx4 hv = *(const halfx4*)(hbase + (size_t)s2 * NHD);
            a0 += wj * (float)hv[0];
            a1 += wj * (float)hv[1];
            a2 += wj * (float)hv[2];
            a3 += wj * (float)hv[3];
        }
        float inv = 1.0f / sm;
        halfx4 o4;
        o4[0] = (_Float16)(a0 * inv);
        o4[1] = (_Float16)(a1 * inv);
        o4[2] = (_Float16)(a2 * inv);
        o4[3] = (_Float16)(a3 * inv);
        *(halfx4*)(out16 + (size_t)g * NHD + lane * 4) = o4;
        int c4 = lane * 4;
#pragma unroll
        for (int j = 0; j < 4; ++j) {
            float v = (float)o4[j];
            bw[BPOS(c4 + j)] = v;
            bw[NHD + BPOS(c4 + j)] = v * v;
        }
    }
    __syncthreads();
    {
        // 512 threads: half 0 reduces sums, half 1 reduces sumsq (1 atomic each)
        int c = tid & 255;
        int half = tid >> 8;
        int pc = BPOS(c);
        float s = 0.0f;
#pragma unroll
        for (int w2 = 0; w2 < 8; ++w2) s += bnpart[w2][half][pc];
        float* sr = sums_cur + (p & (NREP - 1)) * 2 * NHD;
        atomicAdd(&sr[half * NHD + c], s);
    }
}

// ---------------- output head (BN table from bnss) + f16 window shift ----------------

__global__ __launch_bounds__(256) void headout_kernel(const unsigned short* __restrict__ x16,
                                                      const float* __restrict__ bnss,
                                                      const float* __restrict__ Wout,
                                                      const float* __restrict__ bout,
                                                      float* __restrict__ out,
                                                      unsigned short* __restrict__ xx16, int t) {
    __shared__ float bsc[NHD];
    __shared__ float bsh[NHD];
    {
        int c = threadIdx.x;
        bsc[c] = bnss[c];
        bsh[c] = bnss[NHD + c];
    }
    __syncthreads();

    int wave = threadIdx.x >> 6;
    int lane = threadIdx.x & 63;
    int g = blockIdx.x * 4 + wave;
    int c0 = lane * 4;
    halfx4 hv = *(const halfx4*)(x16 + (size_t)g * NHD + c0);
    float vv[4];
#pragma unroll
    for (int j = 0; j < 4; ++j) {
        float x = fmaf((float)hv[j], bsc[c0 + j], bsh[c0 + j]);
        vv[j] = (x > 0.0f) ? x : 0.01f * x;
    }
    float r0 = vv[0] * Wout[(c0 + 0) * NOUT + 0] + vv[1] * Wout[(c0 + 1) * NOUT + 0] +
               vv[2] * Wout[(c0 + 2) * NOUT + 0] + vv[3] * Wout[(c0 + 3) * NOUT + 0];
    float r1 = vv[0] * Wout[(c0 + 0) * NOUT + 1] + vv[1] * Wout[(c0 + 1) * NOUT + 1] +
               vv[2] * Wout[(c0 + 2) * NOUT + 1] + vv[3] * Wout[(c0 + 3) * NOUT + 1];
    float r2 = vv[0] * Wout[(c0 + 0) * NOUT + 2] + vv[1] * Wout[(c0 + 1) * NOUT + 2] +
               vv[2] * Wout[(c0 + 2) * NOUT + 2] + vv[3] * Wout[(c0 + 3) * NOUT + 2];
#pragma unroll
    for (int o = 32; o; o >>= 1) {
        r0 += __shfl_xor(r0, o);
        r1 += __shfl_xor(r1, o);
        r2 += __shfl_xor(r2, o);
    }
    float o0 = r0 + bout[0], o1 = r1 + bout[1], o2 = r2 + bout[2];
    if (lane == 0) {
        float* op = out + ((size_t)g * NT + t) * NOUT;
        op[0] = o0;
        op[1] = o1;
        op[2] = o2;
    }
    float oldv = (lane < NIN) ? h2f(xx16[(size_t)g * K0PAD + lane]) : 0.0f;
    float shifted = __shfl(oldv, lane + 3);
    float newv = (lane < 27) ? shifted : (lane == 27 ? o0 : (lane == 28 ? o1 : o2));
    if (lane < NIN) xx16[(size_t)g * K0PAD + lane] = f2h(newv);
}

// ---------------- launch ----------------

extern "C" void kernel_launch(void* const* d_in, const int* in_sizes, int n_in,
                              void* d_out, int out_size, void* d_ws, size_t ws_size,
                              hipStream_t stream) {
    const float* xx = (const float*)d_in[0];
    const int* src = (const int*)d_in[1];
    const int* dst = (const int*)d_in[2];
    const float* W[4] = {(const float*)d_in[3], (const float*)d_in[8],
                         (const float*)d_in[13], (const float*)d_in[18]};
    const float* al[4] = {(const float*)d_in[4], (const float*)d_in[9],
                          (const float*)d_in[14], (const float*)d_in[19]};
    const float* ar[4] = {(const float*)d_in[5], (const float*)d_in[10],
                          (const float*)d_in[15], (const float*)d_in[20]};
    const float* gamma[4] = {(const float*)d_in[6], (const float*)d_in[11],
                             (const float*)d_in[16], (const float*)d_in[21]};
    const float* beta[4] = {(const float*)d_in[7], (const float*)d_in[12],
                            (const float*)d_in[17], (const float*)d_in[22]};
    const float* W_out = (const float*)d_in[23];
    const float* b_out = (const float*)d_in[24];
    float* out = (float*)d_out;

    // workspace carve
    float* wsf = (float*)d_ws;
    float* el = wsf;                                        // ROWS*NH
    float* er = el + (size_t)ROWS * NH;                     // ROWS*NH
    float* sums = er + (size_t)ROWS * NH;                   // NREP*2*NHD
    float* bnss = sums + NREP * 2 * NHD;                    // 2*NHD (scale|shift)
    unsigned short* h16 = (unsigned short*)(bnss + 2 * NHD); // ROWS*NHD
    unsigned short* act16 = h16 + (size_t)ROWS * NHD;       // ROWS*NHD (attn out)
    unsigned short* xx16 = act16 + (size_t)ROWS * NHD;      // ROWS*K0PAD
    unsigned short* Wt0 = xx16 + (size_t)ROWS * K0PAD;      // 256*K0PAD
    unsigned short* Wt1 = Wt0 + 256 * K0PAD;                // 256*256
    unsigned short* Wt2 = Wt1 + 256 * NHD;
    unsigned short* Wt3 = Wt2 + 256 * NHD;
    int* counts = (int*)(Wt3 + 256 * NHD);                  // NNODES
    int* offsets = counts + NNODES;                         // NNODES+1 (+pad)
    int* cursor = offsets + NNODES + 8;                     // NNODES
    int* csr_src = cursor + NNODES;                         // NEDGES
    const unsigned short* Wt[4] = {Wt0, Wt1, Wt2, Wt3};

    // ---- pack + zero (first), then CSR build ----
    pack_all_kernel<<<dim3(256, 6), 256, 0, stream>>>(xx, W[0], W[1], W[2], W[3],
                                                      xx16,
                                                      (unsigned short*)Wt0,
                                                      (unsigned short*)Wt1,
                                                      (unsigned short*)Wt2,
                                                      (unsigned short*)Wt3,
                                                      counts, cursor, sums);
    count_kernel<<<(NEDGES + 255) / 256, 256, 0, stream>>>(dst, counts, NEDGES);
    scan_kernel<<<1, 1024, 0, stream>>>(counts, offsets, NNODES);
    fill_kernel<<<(NEDGES + 255) / 256, 256, 0, stream>>>(src, dst, offsets, cursor,
                                                          csr_src, NEDGES);

    for (int t = 0; t < NT; ++t) {
        for (int l = 0; l < 4; ++l) {
            const unsigned short* A16 = (l == 0) ? xx16 : act16;
            int K = (l == 0) ? K0PAD : NHD;
            int apply_bn = (l > 0) ? 1 : 0;
            gemm_mfma_kernel<<<ROWS / BM, 256, 0, stream>>>(A16, Wt[l], al[l], ar[l],
                                                            bnss, apply_bn,
                                                            h16, el, er, K);
            attn_kernel<<<ROWS / 8, 512, 0, stream>>>(h16, el, er, offsets, csr_src,
                                                      act16, sums);
            bnfinal_kernel<<<2, 128, 0, stream>>>(sums, gamma[l], beta[l], bnss);
        }
        headout_kernel<<<ROWS / 4, 256, 0, stream>>>(act16, bnss, W_out, b_out,
                                                     out, xx16, t);
    }
}